// Round 10
// baseline (140.533 us; speedup 1.0000x reference)
//
#include <hip/hip_runtime.h>

// HardPartPyramidPooling: x(16,256,32,16,11) fp32, labels(16,32,176) int,
// out(16,256,32,16) fp32.  out[n][c][s][p] = sum/cnt + max (0 if cnt==0),
// max floored at NEG_FILL=-100 (reference init).
//
// R9 = R5's broadcast gather + R7's prep-CSR & DMA staging:
//  - block (n,cg,s): 16-channel x 176 tile, PITCH=180 (16B-aligned rows,
//    c*20 mod 32 -> 8 bank offsets x 2-way = conflict-free), 11.8 KB LDS ->
//    8 blocks/CU = full 32-wave occupancy.
//  - staging: global_load_lds w=16, one 704B row per instruction with
//    exec mask lane<44 (wave-uniform LDS base per row).  No VGPR roundtrip.
//  - meta: 256 B CSR per (n,s) from prep kernel (perm slots zero-padded);
//    gather p=tid>>4, c=tid&15: perm word broadcast across the 16 c-lanes.

constexpr int C   = 256;
constexpr int S   = 32;
constexpr int HW  = 176;        // 16*11
constexpr int P   = 16;
constexpr int ROW = S * HW;     // 5632 floats per (n,c)
constexpr int GC  = 16;         // channels per block
constexpr int PITCH = 180;      // words; 720 B = 45*16 -> DMA-alignable rows
constexpr int REC = 256;        // [0..223] perm u8 (4B-padded, zero-filled)
                                // [224..239] cnt u8, [240..255] off u8
constexpr float NEG_FILL = -100.0f;

// ---------------- prep: build CSR perm per (n,s) ----------------
__global__ __launch_bounds__(256) void prep_kernel(const int* __restrict__ labels,
                                                   unsigned char* __restrict__ ws)
{
    __shared__ int cnt[P], off[P];
    __shared__ unsigned char rec[REC];
    const int tid = threadIdx.x, ns = blockIdx.x;

    int lab = 0, r = 0;
    if (tid < HW) lab = labels[(size_t)ns * HW + tid];
    if (tid < P)  cnt[tid] = 0;
    if (tid < 56) ((unsigned*)rec)[tid] = 0u;      // zero perm area: pad idx=0 safe
    __syncthreads();
    if (tid < HW) r = atomicAdd(&cnt[lab], 1);
    __syncthreads();
    if (tid == 0) {
        int run = 0;
        #pragma unroll
        for (int p = 0; p < P; ++p) { off[p] = run; run += (cnt[p] + 3) & ~3; }
    }
    __syncthreads();
    if (tid < HW) rec[off[lab] + r] = (unsigned char)tid;
    if (tid < P) {
        rec[224 + tid] = (unsigned char)cnt[tid];
        rec[240 + tid] = (unsigned char)off[tid];
    }
    __syncthreads();
    if (tid < REC / 4)
        ((unsigned*)(ws + (size_t)ns * REC))[tid] = ((const unsigned*)rec)[tid];
}

// ---------------- main ----------------
__device__ __forceinline__ void gload_lds16(const void* g, void* l) {
    __builtin_amdgcn_global_load_lds(
        (const __attribute__((address_space(1))) void*)g,
        (__attribute__((address_space(3))) void*)l, 16, 0, 0);
}

__global__ __launch_bounds__(256) void hpp_main(const float* __restrict__ x,
                                                const unsigned char* __restrict__ ws,
                                                float* __restrict__ out)
{
    __shared__ float         tile[GC * PITCH];   // 11520 B
    __shared__ unsigned char rec[REC];           // 256 B

    const int tid = threadIdx.x;
    const int blk = blockIdx.x;          // ((n*16 + cg)*32 + s): x-locality order
    const int s   = blk & 31;
    const int t2  = blk >> 5;
    const int cg  = t2 & 15;
    const int n   = t2 >> 4;
    const int ns  = (n << 5) | s;

    const int lane = tid & 63, wv = tid >> 6;

    // -- meta DMA: wave 0, lanes 0-15 (256 B record; L2/L3-hot) --
    if (tid < 16)
        gload_lds16((const uint4*)(ws + (size_t)ns * REC) + tid, rec);

    // -- tile DMA: wave wv stages rows 4wv..4wv+3; lanes 0-43 = one 704B row --
    const float* xb = x + (size_t)(n * C + cg * GC) * ROW + s * HW;
    if (lane < 44) {
        #pragma unroll
        for (int r = 0; r < 4; ++r) {
            const int row = wv * 4 + r;                 // wave-uniform
            gload_lds16((const float4*)(xb + (size_t)row * ROW) + lane,
                        &tile[row * PITCH]);
        }
    }
    __syncthreads();   // single barrier: drains DMA vmcnt

    // -- gather: p = tid>>4 (4 parts/wave), c = tid&15 (perm word broadcast) --
    const int p = tid >> 4, c = tid & 15;
    const int k    = rec[224 + p];
    const int base = rec[240 + p];                      // 4-aligned
    const unsigned* pw = (const unsigned*)(rec + base);
    const float*    tc = &tile[c * PITCH];

    unsigned w0 = pw[0], w1 = pw[1], w2 = pw[2], w3 = pw[3];  // chain-free preload

    float a0 = 0.f, a1 = 0.f, m0 = NEG_FILL, m1 = NEG_FILL;
    #define CH(w, jb)                                                  \
        do { if (k > (jb)) {                                           \
            float b0 = tc[(w) & 0xFF];                                 \
            float b1 = tc[((w) >> 8) & 0xFF];                          \
            float b2 = tc[((w) >> 16) & 0xFF];                         \
            float b3 = tc[(w) >> 24];                                  \
            a0 += b0; m0 = fmaxf(m0, b0);                              \
            if (k > (jb) + 1) { a1 += b1; m1 = fmaxf(m1, b1); }        \
            if (k > (jb) + 2) { a0 += b2; m0 = fmaxf(m0, b2); }        \
            if (k > (jb) + 3) { a1 += b3; m1 = fmaxf(m1, b3); }        \
        } } while (0)
    CH(w0, 0); CH(w1, 4); CH(w2, 8); CH(w3, 12);
    for (int j = 16; j < k; j += 4) {                   // buckets with k>16
        unsigned w = pw[j >> 2];
        CH(w, j);
    }
    #undef CH

    float res = (k > 0) ? (a0 + a1) / (float)k + fmaxf(m0, m1) : 0.f;
    out[((size_t)(n * C + cg * GC + c) * S + s) * P + p] = res;
}

// ---------------- naive fallback (only if ws too small) ----------------
__global__ void hpp_naive(const float* __restrict__ x,
                          const int* __restrict__ labels,
                          float* __restrict__ out)
{
    int t = blockIdx.x * 256 + threadIdx.x;   // (ns, c, p)
    int p = t & 15, c = (t >> 4) & 255, ns = t >> 12;
    int n = ns >> 5, s = ns & 31;
    const int*   ln  = labels + (size_t)ns * HW;
    const float* row = x + ((size_t)(n * C + c) * S + s) * HW;
    float sum = 0.f, mx = NEG_FILL; int k = 0;
    for (int i = 0; i < HW; ++i)
        if (ln[i] == p) { float v = row[i]; sum += v; mx = fmaxf(mx, v); k++; }
    out[((size_t)(n * C + c) * S + s) * P + p] = k ? sum / (float)k + mx : 0.f;
}

extern "C" void kernel_launch(void* const* d_in, const int* in_sizes, int n_in,
                              void* d_out, int out_size, void* d_ws, size_t ws_size,
                              hipStream_t stream) {
    const float* x      = (const float*)d_in[0];
    const int*   labels = (const int*)d_in[1];
    float*       out    = (float*)d_out;

    const int ns_total = in_sizes[1] / HW;              // 512
    const size_t need  = (size_t)ns_total * REC;        // 128 KB

    if (ws_size >= need) {
        prep_kernel<<<ns_total, 256, 0, stream>>>(labels, (unsigned char*)d_ws);
        hpp_main<<<ns_total * (C / GC), 256, 0, stream>>>(
            x, (const unsigned char*)d_ws, out);
    } else {
        hpp_naive<<<(out_size + 255) / 256, 256, 0, stream>>>(x, labels, out);
    }
}